// Round 1
// baseline (720.881 us; speedup 1.0000x reference)
//
#include <hip/hip_runtime.h>
#include <hip/hip_bf16.h>
#include <stdint.h>

// Problem constants (fixed by the reference)
#define NN   50000
#define RR   50
#define BB   30
#define DIN  64
#define EE   1000000
#define KTOT (BB*DIN + DIN)   // 1984 = 62*32
#define NBW  16               // nodes per workgroup; 50000 = 3125*16 exactly
#define ROWE (KTOT + 8)       // padded LDS row: 1992 elems (3984 B)
#define CPAD 32               // comp row padded 30 -> 32 floats

typedef __attribute__((ext_vector_type(8))) short short8;
typedef __attribute__((ext_vector_type(4))) float floatx4;

#define RFL(x) __builtin_amdgcn_readfirstlane(x)

// ---------------- preprocessing: counting sort of edges by dst ----------------

__global__ void k_hist(const int* __restrict__ dst, const int* __restrict__ et,
                       int* __restrict__ cnt) {
    int e = blockIdx.x * 256 + threadIdx.x;
    if (e < EE) {
        int d = dst[e], r = et[e];
        atomicAdd(&cnt[d * RR + r], 1);
    }
}

// derive dcount from cnt rows (removes 1M atomics from k_hist), then block scan
__global__ void k_scan1(const int* __restrict__ cnt, int* __restrict__ dcount,
                        int* __restrict__ doff, int* __restrict__ bsum) {
    __shared__ int sh[256];
    int t = threadIdx.x;
    int i = blockIdx.x * 256 + t;
    int v = 0;
    if (i < NN) {
        const int* c = cnt + (size_t)i * RR;
#pragma unroll
        for (int r = 0; r < RR; ++r) v += c[r];
        dcount[i] = v;
    }
    sh[t] = v;
    __syncthreads();
    for (int s = 1; s < 256; s <<= 1) {
        int add = (t >= s) ? sh[t - s] : 0;
        __syncthreads();
        sh[t] += add;
        __syncthreads();
    }
    int incl = sh[t];
    if (i < NN) doff[i] = incl - v;
    if (t == 255) bsum[blockIdx.x] = incl;
}

__global__ void k_scan2(int* __restrict__ bsum, int nbv) {
    __shared__ int sh[256];
    int t = threadIdx.x;
    int v = (t < nbv) ? bsum[t] : 0;
    sh[t] = v;
    __syncthreads();
    for (int s = 1; s < 256; s <<= 1) {
        int add = (t >= s) ? sh[t - s] : 0;
        __syncthreads();
        sh[t] += add;
        __syncthreads();
    }
    if (t < nbv) bsum[t] = sh[t] - v;
}

__global__ void k_scan3(int* __restrict__ doff, const int* __restrict__ bsum) {
    int i = blockIdx.x * 256 + threadIdx.x;
    if (i < NN) doff[i] += bsum[blockIdx.x];
}

// records: .x = src | (rel<<16)  (src<65536, rel<50), .y = bits of a = 1/cnt(d,r)
__global__ void k_scatter(const int* __restrict__ src, const int* __restrict__ dst,
                          const int* __restrict__ et, const int* __restrict__ cnt,
                          const int* __restrict__ doff, int* __restrict__ cursor,
                          int2* __restrict__ ep2) {
    int e = blockIdx.x * 256 + threadIdx.x;
    if (e < EE) {
        int d = dst[e], r = et[e], s = src[e];
        int p = doff[d] + atomicAdd(&cursor[d], 1);
        float a = 1.0f / (float)cnt[d * RR + r];
        ep2[p] = make_int2(s | (r << 16), __float_as_int(a));
    }
}

__global__ void k_cast_x(const float* __restrict__ x, __hip_bfloat16* __restrict__ h) {
    int i = blockIdx.x * 256 + threadIdx.x;
    if (i < NN * DIN) h[i] = __float2bfloat16(x[i]);
}

// all 3 layers' comp [R,30] fp32 -> padded [3][R,32] fp32
__global__ void k_prep_comp3(const float* __restrict__ c0, const float* __restrict__ c1,
                             const float* __restrict__ c2, float* __restrict__ cp) {
    int idx = blockIdx.x * 256 + threadIdx.x;
    if (idx < 3 * RR * CPAD) {
        int l = idx / (RR * CPAD);
        int rem = idx - l * (RR * CPAD);
        int r = rem / CPAD, i = rem - r * CPAD;
        const float* c = (l == 0) ? c0 : (l == 1) ? c1 : c2;
        cp[idx] = (i < BB) ? c[r * BB + i] : 0.f;
    }
}

// all 3 layers' transposed bf16 weights:
// wt rows [0,64): layer0; [64,128): layer1; [128,144): layer2 (dout=8, 16 padded rows)
__global__ void k_prep_w3(const float* __restrict__ b0, const float* __restrict__ r0,
                          const float* __restrict__ b1, const float* __restrict__ r1,
                          const float* __restrict__ b2, const float* __restrict__ r2,
                          short* __restrict__ wt) {
    int idx = blockIdx.x * 256 + threadIdx.x;
    if (idx >= 144 * KTOT) return;
    int row = idx / KTOT, k = idx - row * KTOT;
    const float* bs; const float* rt; int o, dout;
    if (row < 64)       { bs = b0; rt = r0; o = row;        dout = 64; }
    else if (row < 128) { bs = b1; rt = r1; o = row - 64;   dout = 64; }
    else                { bs = b2; rt = r2; o = row - 128;  dout = 8;  }
    float v = 0.f;
    if (o < dout)
        v = (k < BB * DIN) ? bs[k * dout + o] : rt[(k - BB * DIN) * dout + o];
    __hip_bfloat16 hb = __float2bfloat16(v);
    wt[idx] = *reinterpret_cast<const short*>(&hb);
}

// ---------------- fused per-layer kernel ----------------
// 512 threads = 8 waves, 2 blocks/CU (LDS-capped) -> 16 waves/CU, 128 VGPR/wave.
// Phase 1: wave wv owns nodes (wv, wv+8). Both nodes' 4-edge chunk lists
//   (tails included as a=0-masked chunks) form ONE pipelined stream:
//   records for chunk t+2 prefetched (scalar s_load, mask applied at load),
//   gathers for chunk t+1 in flight during chunk t's FMAs. Pipeline never
//   drains between nodes; no serial tail path.
// Phase 2: 8 waves = 4 col-tiles x 2 K-parts (DOUT=64) or 8 K-parts (DOUT=8);
//   partials reduced through LDS with stride-6 layout.

// load+mask 4 records of chunk u (all scalar ops; ghost edges get src=0, a=0)
#define LOADREC(u, q0, q1, q2, q3) do {                                         \
    const int _u  = (u);                                                        \
    const int _b  = (_u < nchA) ? (begA + 4*_u) : (begB + 4*(_u - nchA));       \
    const int _rm = (_u < nchA) ? (cntA - 4*_u) : (cntB - 4*(_u - nchA));       \
    q0 = ep2[_b];     q1 = ep2[_b + 1];                                         \
    q2 = ep2[_b + 2]; q3 = ep2[_b + 3];                                         \
    q1.x = (_rm > 1) ? q1.x : 0;  q1.y = (_rm > 1) ? q1.y : 0;                  \
    q2.x = (_rm > 2) ? q2.x : 0;  q2.y = (_rm > 2) ? q2.y : 0;                  \
    q3.x = (_rm > 3) ? q3.x : 0;  q3.y = (_rm > 3) ? q3.y : 0;                  \
} while (0)

// issue gather for one record (raw bf16 bits; cvt deferred to FMA site)
#define GATH(q) ((unsigned)xin16[(RFL((q).x) & 0xFFFF) * DIN + lane])

// one edge's rank-1 update into ACC (comp row via scalar loads)
#define EDGE_FMA(q, g, ACC) do {                                                \
    const int   _sx = RFL((q).x);                                               \
    const float _a  = __int_as_float(RFL((q).y));                               \
    const floatx4* _c = (const floatx4*)(compP + (_sx >> 16) * CPAD);           \
    const float _g  = __uint_as_float((g) << 16);   /* bf16 -> f32 */           \
    const float _xv = _g * _a;                                                  \
    const floatx4 _w = {_xv, _xv, _xv, _xv};                                    \
    ACC[0] = _c[0] * _w + ACC[0];  ACC[1] = _c[1] * _w + ACC[1];                \
    ACC[2] = _c[2] * _w + ACC[2];  ACC[3] = _c[3] * _w + ACC[3];                \
    ACC[4] = _c[4] * _w + ACC[4];  ACC[5] = _c[5] * _w + ACC[5];                \
    ACC[6] = _c[6] * _w + ACC[6];  ACC[7] = _c[7] * _w + ACC[7];                \
} while (0)

template <int DOUT, bool RELU>
__global__ __launch_bounds__(512, 4)
void k_fused(const __hip_bfloat16* __restrict__ xin,
             const int2* __restrict__ ep2,
             const int* __restrict__ doff, const int* __restrict__ dcount,
             const float* __restrict__ compP,    // [R, 32] fp32 padded
             const short* __restrict__ Wt,       // [DPAD][KTOT] bf16 (transposed)
             const float* __restrict__ bias,     // [DOUT]
             void* __restrict__ outp) {
    __shared__ __align__(16) char smem_raw[NBW * ROWE * 2];   // 63744 B
    auto t_tile = reinterpret_cast<__hip_bfloat16(*)[ROWE]>(smem_raw);
    const unsigned short* xin16 = reinterpret_cast<const unsigned short*>(xin);
    const int tid  = threadIdx.x;
    const int lane = tid & 63;
    const int wv   = RFL(tid >> 6);          // 0..7
    const int node0 = blockIdx.x * NBW;
    const int nA = node0 + wv;
    const int nB = node0 + wv + 8;

    // ---- phase 1: two nodes per wave, unified pipelined chunk stream ----
    {
        floatx4 accA[8], accB[8];
#pragma unroll
        for (int u = 0; u < 8; ++u) {
            accA[u] = (floatx4){0.f, 0.f, 0.f, 0.f};
            accB[u] = (floatx4){0.f, 0.f, 0.f, 0.f};
        }
        // self rows: issue early, consumed at epilogue
        const unsigned selfA = (unsigned)xin16[nA * DIN + lane];
        const unsigned selfB = (unsigned)xin16[nB * DIN + lane];

        const int begA = RFL(doff[nA]), cntA = RFL(dcount[nA]);
        const int begB = RFL(doff[nB]), cntB = RFL(dcount[nB]);
        const int nchA = (cntA + 3) >> 2;
        const int nchB = (cntB + 3) >> 2;
        const int T = nchA + nchB;

        if (T > 0) {
            int2 c0, c1, c2, c3, n0, n1, n2, n3;
            LOADREC(0, c0, c1, c2, c3);
            unsigned g0 = GATH(c0), g1 = GATH(c1), g2 = GATH(c2), g3 = GATH(c3);
            { const int u1 = (1 < T) ? 1 : 0; LOADREC(u1, n0, n1, n2, n3); }

            for (int t = 0; t < T; ++t) {
                // prefetch records for chunk t+2 (clamped)
                int2 p0, p1, p2, p3;
                { const int u2 = (t + 2 < T) ? (t + 2) : (T - 1);
                  LOADREC(u2, p0, p1, p2, p3); }
                // issue gathers for chunk t+1
                unsigned h0 = GATH(n0), h1 = GATH(n1), h2 = GATH(n2), h3 = GATH(n3);
                // FMA chunk t into the owning node's accumulator (uniform branch)
                if (t < nchA) {
                    EDGE_FMA(c0, g0, accA); EDGE_FMA(c1, g1, accA);
                    EDGE_FMA(c2, g2, accA); EDGE_FMA(c3, g3, accA);
                } else {
                    EDGE_FMA(c0, g0, accB); EDGE_FMA(c1, g1, accB);
                    EDGE_FMA(c2, g2, accB); EDGE_FMA(c3, g3, accB);
                }
                // rotate pipeline
                c0 = n0; c1 = n1; c2 = n2; c3 = n3;
                n0 = p0; n1 = p1; n2 = p2; n3 = p3;
                g0 = h0; g1 = h1; g2 = h2; g3 = h3;
            }
        }
        // epilogue: write both rows
#pragma unroll
        for (int b = 0; b < BB; ++b)
            t_tile[wv][b * DIN + lane] = __float2bfloat16(accA[b >> 2][b & 3]);
        t_tile[wv][BB * DIN + lane] =
            __float2bfloat16(__uint_as_float(selfA << 16));
#pragma unroll
        for (int b = 0; b < BB; ++b)
            t_tile[wv + 8][b * DIN + lane] = __float2bfloat16(accB[b >> 2][b & 3]);
        t_tile[wv + 8][BB * DIN + lane] =
            __float2bfloat16(__uint_as_float(selfB << 16));
    }
    __syncthreads();

    // ---- phase 2: MFMA 16x16x32 bf16, K = 1984 (62 steps) over 8 waves ----
    const int m = lane & 15;
    const int q = lane >> 4;
    int kk0, nsteps, col_base, kpart;
    if (DOUT == 64) {
        kpart = wv >> 2;                 // 0..1
        col_base = (wv & 3) * 16;
        kk0    = kpart * 31;
        nsteps = 31;
    } else {
        kpart = wv;                      // 0..7
        col_base = 0;
        kk0    = (kpart < 7) ? kpart * 8 : 55;   // 6*8=48, then 7+7
        nsteps = (kpart < 6) ? 8 : 7;
    }
    const __hip_bfloat16* arow = &t_tile[m][q * 8];
    const short* brow = Wt + (size_t)(col_base + m) * KTOT + q * 8;

    floatx4 acc0 = {0.f, 0.f, 0.f, 0.f};
    floatx4 acc1 = {0.f, 0.f, 0.f, 0.f};
    int s = 0;
    for (; s + 2 <= nsteps; s += 2) {
        const int kk = kk0 + s;
        short8 a0 = *reinterpret_cast<const short8*>(arow + kk * 32);
        short8 b0 = *reinterpret_cast<const short8*>(brow + kk * 32);
        short8 a1 = *reinterpret_cast<const short8*>(arow + (kk + 1) * 32);
        short8 b1 = *reinterpret_cast<const short8*>(brow + (kk + 1) * 32);
        acc0 = __builtin_amdgcn_mfma_f32_16x16x32_bf16(a0, b0, acc0, 0, 0, 0);
        acc1 = __builtin_amdgcn_mfma_f32_16x16x32_bf16(a1, b1, acc1, 0, 0, 0);
    }
    if (s < nsteps) {
        const int kk = kk0 + s;
        short8 a0 = *reinterpret_cast<const short8*>(arow + kk * 32);
        short8 b0 = *reinterpret_cast<const short8*>(brow + kk * 32);
        acc0 = __builtin_amdgcn_mfma_f32_16x16x32_bf16(a0, b0, acc0, 0, 0, 0);
    }
    floatx4 P = acc0 + acc1;

    __syncthreads();                       // all t_tile reads done
    float* red = (float*)smem_raw;         // reuse LDS; stride-6 layout

    if (DOUT == 64) {
        // 2 K-parts per col group; part 1 writes, part 0 reduces
        if (kpart == 1) {
            const int off = ((wv & 3) * 64 + lane) * 6;
            red[off] = P[0]; red[off + 1] = P[1]; red[off + 2] = P[2]; red[off + 3] = P[3];
        }
        __syncthreads();
        if (kpart == 0) {
            const int off = ((wv & 3) * 64 + lane) * 6;
            P[0] += red[off]; P[1] += red[off + 1];
            P[2] += red[off + 2]; P[3] += red[off + 3];
            const int o = col_base + m;
            const float bi = bias[o];
#pragma unroll
            for (int r = 0; r < 4; ++r) {
                const int n = node0 + q * 4 + r;
                float v = P[r] + bi;
                if (RELU) {
                    v = fmaxf(v, 0.f);
                    reinterpret_cast<__hip_bfloat16*>(outp)[(size_t)n * DOUT + o] =
                        __float2bfloat16(v);
                } else {
                    reinterpret_cast<float*>(outp)[(size_t)n * DOUT + o] = v;
                }
            }
        }
    } else {
        if (kpart > 0) {
            const int off = ((kpart - 1) * 64 + lane) * 6;
            red[off] = P[0]; red[off + 1] = P[1]; red[off + 2] = P[2]; red[off + 3] = P[3];
        }
        __syncthreads();
        if (kpart == 0) {
#pragma unroll
            for (int w = 0; w < 7; ++w) {
                const int off = (w * 64 + lane) * 6;
                P[0] += red[off]; P[1] += red[off + 1];
                P[2] += red[off + 2]; P[3] += red[off + 3];
            }
            if (m < DOUT) {
                const int o = m;
                const float bi = bias[o];
#pragma unroll
                for (int r = 0; r < 4; ++r) {
                    const int n = node0 + q * 4 + r;
                    reinterpret_cast<float*>(outp)[(size_t)n * DOUT + o] = P[r] + bi;
                }
            }
        }
    }
}

// ---------------- log_softmax over C=8 ----------------
__global__ void k_lsm(const float* __restrict__ pre, float* __restrict__ out) {
    int n = blockIdx.x * 256 + threadIdx.x;
    if (n < NN) {
        float v[8];
        float mx = -1e30f;
#pragma unroll
        for (int c = 0; c < 8; ++c) { v[c] = pre[n * 8 + c]; mx = fmaxf(mx, v[c]); }
        float s = 0.f;
#pragma unroll
        for (int c = 0; c < 8; ++c) s += expf(v[c] - mx);
        float ls = logf(s);
#pragma unroll
        for (int c = 0; c < 8; ++c) out[n * 8 + c] = v[c] - mx - ls;
    }
}

// ---------------- launch ----------------
extern "C" void kernel_launch(void* const* d_in, const int* in_sizes, int n_in,
                              void* d_out, int out_size, void* d_ws, size_t ws_size,
                              hipStream_t stream) {
    const float* x     = (const float*)d_in[0];
    const int*   eidx  = (const int*)d_in[1];
    const int*   etype = (const int*)d_in[2];
    const float* bases0 = (const float*)d_in[3];
    const float* comp0  = (const float*)d_in[4];
    const float* root0  = (const float*)d_in[5];
    const float* bias0  = (const float*)d_in[6];
    const float* bases1 = (const float*)d_in[7];
    const float* comp1  = (const float*)d_in[8];
    const float* root1  = (const float*)d_in[9];
    const float* bias1  = (const float*)d_in[10];
    const float* bases2 = (const float*)d_in[11];
    const float* comp2  = (const float*)d_in[12];
    const float* root2  = (const float*)d_in[13];
    const float* bias2  = (const float*)d_in[14];
    const int* srcp = eidx;
    const int* dstp = eidx + EE;

    char* p = (char*)d_ws;
    auto carve = [&](size_t bytes) -> char* {
        char* r = p;
        p += (bytes + 255) & ~(size_t)255;
        return r;
    };
    int*  cnt    = (int*)carve((size_t)NN * RR * sizeof(int));   // 10 MB
    int*  dcount = (int*)carve((size_t)NN * sizeof(int));
    int*  cursor = (int*)carve((size_t)NN * sizeof(int));
    int*  doff   = (int*)carve((size_t)NN * sizeof(int));
    int*  bsum   = (int*)carve(256 * sizeof(int));
    int2* ep2    = (int2*)carve((size_t)(EE + 8) * sizeof(int2)); // 8 MB (+overrun pad)
    __hip_bfloat16* h0 = (__hip_bfloat16*)carve((size_t)NN * DIN * 2);
    __hip_bfloat16* h1 = (__hip_bfloat16*)carve((size_t)NN * DIN * 2);
    __hip_bfloat16* h2 = (__hip_bfloat16*)carve((size_t)NN * DIN * 2);
    float* pre = (float*)carve((size_t)NN * 8 * sizeof(float));
    short* wtA = (short*)carve((size_t)144 * KTOT * sizeof(short));  // 3 layers stacked
    float* cpA = (float*)carve((size_t)3 * RR * CPAD * sizeof(float));

    // cnt, dcount, cursor are adjacent in the carve order -> one memset
    hipMemsetAsync(cnt, 0, (size_t)NN * (RR + 2) * sizeof(int) + 512, stream);

    const int EB = (EE + 255) / 256;   // 3907
    const int NB = (NN + 255) / 256;   // 196
    k_hist<<<EB, 256, 0, stream>>>(dstp, etype, cnt);
    k_scan1<<<NB, 256, 0, stream>>>(cnt, dcount, doff, bsum);
    k_scan2<<<1, 256, 0, stream>>>(bsum, NB);
    k_scan3<<<NB, 256, 0, stream>>>(doff, bsum);
    k_scatter<<<EB, 256, 0, stream>>>(srcp, dstp, etype, cnt, doff, cursor, ep2);
    k_cast_x<<<(NN * DIN + 255) / 256, 256, 0, stream>>>(x, h0);
    k_prep_comp3<<<(3 * RR * CPAD + 255) / 256, 256, 0, stream>>>(comp0, comp1, comp2, cpA);
    k_prep_w3<<<(144 * KTOT + 255) / 256, 256, 0, stream>>>(bases0, root0, bases1, root1,
                                                            bases2, root2, wtA);

    short* wt0 = wtA;
    short* wt1 = wtA + (size_t)64 * KTOT;
    short* wt2 = wtA + (size_t)128 * KTOT;
    float* cp0 = cpA;
    float* cp1 = cpA + RR * CPAD;
    float* cp2 = cpA + 2 * RR * CPAD;

    const int NF = NN / NBW;   // 3125 (exact)
    k_fused<64, true ><<<NF, 512, 0, stream>>>(h0, ep2, doff, dcount, cp0, wt0, bias0, (void*)h1);
    k_fused<64, true ><<<NF, 512, 0, stream>>>(h1, ep2, doff, dcount, cp1, wt1, bias1, (void*)h2);
    k_fused<8,  false><<<NF, 512, 0, stream>>>(h2, ep2, doff, dcount, cp2, wt2, bias2, (void*)pre);
    k_lsm<<<NB, 256, 0, stream>>>(pre, (float*)d_out);
}